// Round 6
// baseline (306.287 us; speedup 1.0000x reference)
//
#include <hip/hip_runtime.h>

// DeepFM fused ranker, fp32.
// R10: widen the block, not the grid. Ledger: R4 fused (32 rows, 4 waves,
// grid 512, 8 waves/CU) = best at ~55-60 us kernel; all grid-raising attempts
// died on VGPR allocation (R7 spills / R8 balloon to 200). This keeps R4's
// grid=512 / 2 blocks/CU but uses 512-thread blocks (8 waves): 16 waves/CU if
// VGPR <= 128. Per-wave work halves: phase A 4 rows/wave (#pragma unroll 1
// on the row loop to stop live-range stacking), B 16 neurons/wave, C 8/wave.
// Bank checks: B-act reads 12*rh mod 32 = exact 32-bank cover; C-act and h1
// stores 2-way (free per m136). LDS 27.3 KB x 2 blocks = 54.6 KB.

typedef float v2f __attribute__((ext_vector_type(2)));
static __device__ __forceinline__ v2f bc2(float x) { v2f r; r.x = x; r.y = x; return r; }
static __device__ __forceinline__ float relu1(float x) { return fmaxf(x, 0.f); }

#define ROWS_PER_BLOCK 32
#define DI_STRIDE 204            // floats; 51 float4
#define H1_STRIDE 132            // floats; 33 float4

// ---- pre-pass: pair-transposed packed weights, 8-wave layout ----
// W1p[g*800 + k4*16 + jp*2 + s], g=0..7 (16 neurons each), jp=0..7:
//   {W1[j0][c], W1[j0+1][c], W1[j0][c+1], W1[j0+1][c+1]},
//   j0 = g*16 + 2*jp, c = 4*k4 + 2*s.
// W2p[g*256 + k4*8 + jp*2 + s], g=0..7 (8 neurons each), jp=0..3:
//   same with j0 = g*8 + 2*jp, row len 128.
__global__ void pack_weights(const float* __restrict__ W1, const float* __restrict__ W2,
                             float4* __restrict__ W1p, float4* __restrict__ W2p) {
    const int idx = blockIdx.x * blockDim.x + threadIdx.x;
    if (idx < 6400) {
        const int s = idx & 1, jp = (idx >> 1) & 7, k4 = (idx >> 4) % 50, g = idx / 800;
        const int j0 = g * 16 + 2 * jp, c = 4 * k4 + 2 * s;
        W1p[idx] = make_float4(W1[j0 * 200 + c],     W1[(j0 + 1) * 200 + c],
                               W1[j0 * 200 + c + 1], W1[(j0 + 1) * 200 + c + 1]);
    }
    if (idx < 2048) {
        const int s = idx & 1, jp = (idx >> 1) & 3, k4 = (idx >> 3) & 31, g = idx >> 8;
        const int j0 = g * 8 + 2 * jp, c = 4 * k4 + 2 * s;
        W2p[idx] = make_float4(W2[j0 * 128 + c],     W2[(j0 + 1) * 128 + c],
                               W2[j0 * 128 + c + 1], W2[(j0 + 1) * 128 + c + 1]);
    }
}

__global__ __launch_bounds__(512) void deepfm_kernel(
    const int* __restrict__ user_id, const int* __restrict__ item_id,
    const int* __restrict__ gender_, const int* __restrict__ age_,
    const int* __restrict__ occ_, const int* __restrict__ genre_ids,
    const float* __restrict__ genre_mask, const float* __restrict__ dense,
    const float* __restrict__ fo_user, const float* __restrict__ fo_item,
    const float* __restrict__ fo_gender, const float* __restrict__ fo_age,
    const float* __restrict__ fo_occ, const float* __restrict__ fo_genre,
    const float* __restrict__ emb_user, const float* __restrict__ emb_item,
    const float* __restrict__ emb_gender, const float* __restrict__ emb_age,
    const float* __restrict__ emb_occ, const float* __restrict__ emb_genre,
    const float* __restrict__ dense_W, const float* __restrict__ dense_b,
    const float4* __restrict__ W1p, const float* __restrict__ b1,
    const float4* __restrict__ W2p, const float* __restrict__ b2,
    const float* __restrict__ Wout, const float* __restrict__ bout,
    float* __restrict__ out, int B)
{
    __shared__ float lds_di[ROWS_PER_BLOCK][DI_STRIDE];   // 26.1 KB; h1[32][132] overlays
    __shared__ float lds_rs[ROWS_PER_BLOCK];
    __shared__ float lds_part[ROWS_PER_BLOCK][8];

    const int tid = threadIdx.x;
    const int wid = tid >> 6;          // 0..7
    const int lane = tid & 63;
    const int blockRow0 = blockIdx.x * ROWS_PER_BLOCK;

    // ---------------- Phase A: gather + FM first/second order (wave owns 4 rows) ----
    {
        const int rowBase = blockRow0 + wid * 4;

        #pragma unroll 1
        for (int r = 0; r < 4; ++r) {
            int row = rowBase + r; if (row >= B) row = B - 1;
            const int ri = wid * 4 + r;

            const int uid = user_id[row], iid = item_id[row];
            const int gg = gender_[row], aa = age_[row], oo = occ_[row];

            int gid[6]; float mk[6]; float msum = 0.f;
            #pragma unroll
            for (int t = 0; t < 6; ++t) {
                gid[t] = genre_ids[row * 6 + t];
                mk[t]  = genre_mask[row * 6 + t];
                msum  += mk[t];
            }
            const float inv_den = 1.0f / fmaxf(msum, 1.0f);

            float pe_sum = 0.f, pe_sq = 0.f;
            {
                float v = (lane < 32) ? emb_user[(size_t)uid * 32 + lane]
                                      : emb_item[(size_t)iid * 32 + (lane - 32)];
                lds_di[ri][lane] = v;
                pe_sum += v; pe_sq += v * v;
            }
            {
                float v = (lane < 32) ? emb_gender[gg * 32 + lane]
                                      : emb_age[aa * 32 + (lane - 32)];
                lds_di[ri][64 + lane] = v;
                pe_sum += v; pe_sq += v * v;
            }
            {
                float v;
                if (lane < 32) {
                    v = emb_occ[oo * 32 + lane];
                } else {
                    const int d = lane - 32;
                    float s = 0.f;
                    #pragma unroll
                    for (int t = 0; t < 6; ++t) s += mk[t] * emb_genre[gid[t] * 32 + d];
                    v = s * inv_den;
                }
                lds_di[ri][128 + lane] = v;
                pe_sum += v; pe_sq += v * v;
            }
            if (lane < 8) lds_di[ri][192 + lane] = dense[(size_t)row * 8 + lane];

            float s2 = pe_sum + __shfl_xor(pe_sum, 32);
            float ss = pe_sq  + __shfl_xor(pe_sq, 32);
            float t2 = 0.5f * (s2 * s2 - ss);
            #pragma unroll
            for (int off = 16; off >= 1; off >>= 1) t2 += __shfl_xor(t2, off);

            float fo = fo_user[uid] + fo_item[iid] + fo_gender[gg]
                     + fo_age[aa] + fo_occ[oo];
            float fg = 0.f;
            #pragma unroll
            for (int t = 0; t < 6; ++t) fg += mk[t] * fo_genre[gid[t]];
            fo += fg * inv_den;
            float dd = 0.f;
            #pragma unroll
            for (int j = 0; j < 8; ++j) dd += dense[(size_t)row * 8 + j] * dense_W[j];
            fo += dd + dense_b[0];

            if (lane == 0) lds_rs[ri] = fo + t2;
        }
    }
    __syncthreads();

    // ---------------- Phase B: h1 = relu(deep_in @ W1^T + b1) ----------------------
    // wave owns neurons [16*wid, 16*wid+16); jp1=lane&7 -> pair {2jp,2jp+1},
    // rh=lane>>3 -> rows {rh+8r}, r=0..3. Per k4: 4 act b128 (8 distinct rows,
    // banks 12rh mod 32 = full 32-bank cover, conflict-free) + 2 weight b128
    // (8 distinct addrs, 8-lane broadcast, coalesced) + 16 v_pk_fma.
    const int jp1 = lane & 7;
    const int rh  = lane >> 3;

    v2f acc[4];
    #pragma unroll
    for (int r = 0; r < 4; ++r) acc[r] = bc2(0.f);

    {
        const float4* __restrict__ W1b = W1p + wid * 800;
        const float4* __restrict__ dv = reinterpret_cast<const float4*>(&lds_di[0][0]); // stride 51

        for (int k4 = 0; k4 < 50; ++k4) {
            const float4 wa = W1b[k4 * 16 + jp1 * 2 + 0];   // {j0k0,j1k0,j0k1,j1k1}
            const float4 wb = W1b[k4 * 16 + jp1 * 2 + 1];   // {j0k2,j1k2,j0k3,j1k3}
            const v2f w0 = { wa.x, wa.y }, w1 = { wa.z, wa.w };
            const v2f w2 = { wb.x, wb.y }, w3 = { wb.z, wb.w };
            #pragma unroll
            for (int r = 0; r < 4; ++r) {
                const float4 a = dv[(rh + 8 * r) * 51 + k4];
                acc[r] = __builtin_elementwise_fma(w0, bc2(a.x), acc[r]);
                acc[r] = __builtin_elementwise_fma(w1, bc2(a.y), acc[r]);
                acc[r] = __builtin_elementwise_fma(w2, bc2(a.z), acc[r]);
                acc[r] = __builtin_elementwise_fma(w3, bc2(a.w), acc[r]);
            }
        }
    }
    __syncthreads();   // all deep_in reads done; overlay h1

    float* __restrict__ h1b = &lds_di[0][0];   // h1[row][j] at row*132 + j
    {
        const int j0 = wid * 16 + 2 * jp1;
        const float2 bb = *reinterpret_cast<const float2*>(b1 + j0);
        #pragma unroll
        for (int r = 0; r < 4; ++r) {
            const int row = rh + 8 * r;
            *reinterpret_cast<float2*>(h1b + row * H1_STRIDE + j0) =
                make_float2(relu1(acc[r].x + bb.x), relu1(acc[r].y + bb.y));
        }
    }
    __syncthreads();

    // ---------------- Phase C: h2 = relu(h1 @ W2^T + b2) ---------------------------
    // wave owns neurons [8*wid, 8*wid+8); jp2=lane&3 -> pair, rh2=lane>>2 ->
    // rows {rh2+16t}, t=0..1. Act reads 16 distinct rows, banks 4*rh2 mod 32 ->
    // 2-way (free).
    const int jp2 = lane & 3;
    const int rh2 = lane >> 2;

    v2f acc2[2];
    acc2[0] = bc2(0.f); acc2[1] = bc2(0.f);

    {
        const float4* __restrict__ W2b = W2p + wid * 256;
        const float4* __restrict__ h1v = reinterpret_cast<const float4*>(h1b); // stride 33

        for (int k4 = 0; k4 < 32; ++k4) {
            const float4 wa = W2b[k4 * 8 + jp2 * 2 + 0];
            const float4 wb = W2b[k4 * 8 + jp2 * 2 + 1];
            const v2f w0 = { wa.x, wa.y }, w1 = { wa.z, wa.w };
            const v2f w2 = { wb.x, wb.y }, w3 = { wb.z, wb.w };
            #pragma unroll
            for (int t = 0; t < 2; ++t) {
                const float4 h = h1v[(rh2 + 16 * t) * 33 + k4];
                acc2[t] = __builtin_elementwise_fma(w0, bc2(h.x), acc2[t]);
                acc2[t] = __builtin_elementwise_fma(w1, bc2(h.y), acc2[t]);
                acc2[t] = __builtin_elementwise_fma(w2, bc2(h.z), acc2[t]);
                acc2[t] = __builtin_elementwise_fma(w3, bc2(h.w), acc2[t]);
            }
        }
    }

    // ---------------- Phase D: Wout dot + combine ----------------------------------
    {
        const int j0 = wid * 8 + 2 * jp2;
        const float2 bb2 = *reinterpret_cast<const float2*>(b2 + j0);
        const float2 wo  = *reinterpret_cast<const float2*>(Wout + j0);
        #pragma unroll
        for (int t = 0; t < 2; ++t) {
            const float h2x = relu1(acc2[t].x + bb2.x);
            const float h2y = relu1(acc2[t].y + bb2.y);
            float v = wo.x * h2x + wo.y * h2y;
            v += __shfl_xor(v, 1); v += __shfl_xor(v, 2);
            if (jp2 == 0) lds_part[rh2 + 16 * t][wid] = v;
        }
    }
    __syncthreads();

    if (tid < ROWS_PER_BLOCK) {
        const int row = blockRow0 + tid;
        if (row < B) {
            float deep = bout[0];
            #pragma unroll
            for (int w = 0; w < 8; ++w) deep += lds_part[tid][w];
            out[row] = deep + lds_rs[tid];
        }
    }
}

extern "C" void kernel_launch(void* const* d_in, const int* in_sizes, int n_in,
                              void* d_out, int out_size, void* d_ws, size_t ws_size,
                              hipStream_t stream) {
    const int B = in_sizes[0];

    float4* W1p = reinterpret_cast<float4*>(d_ws);                  // 6400 float4 = 100 KB
    float4* W2p = reinterpret_cast<float4*>((char*)d_ws + 102400);  // 2048 float4 = 32 KB

    pack_weights<<<25, 256, 0, stream>>>(
        (const float*)d_in[22], (const float*)d_in[24], W1p, W2p);

    const int grid = (B + ROWS_PER_BLOCK - 1) / ROWS_PER_BLOCK;  // 512 at B=16384
    deepfm_kernel<<<grid, 512, 0, stream>>>(
        (const int*)d_in[0],  (const int*)d_in[1],  (const int*)d_in[2],
        (const int*)d_in[3],  (const int*)d_in[4],  (const int*)d_in[5],
        (const float*)d_in[6],  (const float*)d_in[7],
        (const float*)d_in[8],  (const float*)d_in[9],  (const float*)d_in[10],
        (const float*)d_in[11], (const float*)d_in[12], (const float*)d_in[13],
        (const float*)d_in[14], (const float*)d_in[15], (const float*)d_in[16],
        (const float*)d_in[17], (const float*)d_in[18], (const float*)d_in[19],
        (const float*)d_in[20], (const float*)d_in[21],
        W1p, (const float*)d_in[23],
        W2p, (const float*)d_in[25],
        (const float*)d_in[26], (const float*)d_in[27],
        (float*)d_out, B);
}

// Round 7
// 255.202 us; speedup vs baseline: 1.2002x; 1.2002x over previous
//
#include <hip/hip_runtime.h>

// DeepFM fused ranker, fp32.
// R11: reduce actual register pressure instead of capping it. Ledger invariant
// R4..R10: phase-A's fully-unrolled row loop sets VGPR ~200 (25 live/row x 8);
// external caps (launch_bounds, 512t block) -> spill bombs; uncapped -> 2
// waves/SIMD so grid-raising never materialized as occupancy. Fix at source:
//  - #pragma unroll 1 on phase-A row loop, ids loaded in-loop (no arrays).
//  - #pragma unroll 2 on B/C k4 loops (bounds pipelining; proven shape in R9).
//  - ROWS16 / grid 1024 / 256 threads (R8 geometry, phases B/C/D verbatim —
//    never spilled at 256t). Target VGPR ~80-100 -> 16 waves/CU real.

typedef float v2f __attribute__((ext_vector_type(2)));
static __device__ __forceinline__ v2f bc2(float x) { v2f r; r.x = x; r.y = x; return r; }
static __device__ __forceinline__ float relu1(float x) { return fmaxf(x, 0.f); }

#define ROWS_PER_BLOCK 16
#define ROWS_PER_WAVE 4
#define DI_STRIDE 204            // floats; 51 float4
#define H1_STRIDE 132            // floats; 33 float4

// ---- pre-pass: pair-transposed packed weights (R4 layout) ----
// W1p[((wid*50+k4)*16+jp)*2+s] = {W1[j0][c],W1[j1][c],W1[j0][c+1],W1[j1][c+1]}
//   j0 = 32*wid + 2*jp, c = 4*k4 + 2*s
// W2p[((wid*32+k4)*8+jp)*2+s]  = same with j0 = 16*wid + 2*jp, row len 128
__global__ void pack_weights(const float* __restrict__ W1, const float* __restrict__ W2,
                             float4* __restrict__ W1p, float4* __restrict__ W2p) {
    const int idx = blockIdx.x * blockDim.x + threadIdx.x;
    if (idx < 6400) {
        const int s = idx & 1, jp = (idx >> 1) & 15, k4 = (idx >> 5) % 50, w = idx / 1600;
        const int j0 = w * 32 + 2 * jp, c = 4 * k4 + 2 * s;
        W1p[idx] = make_float4(W1[j0 * 200 + c],     W1[(j0 + 1) * 200 + c],
                               W1[j0 * 200 + c + 1], W1[(j0 + 1) * 200 + c + 1]);
    }
    if (idx < 2048) {
        const int s = idx & 1, jp = (idx >> 1) & 7, k4 = (idx >> 4) & 31, w = idx >> 9;
        const int j0 = w * 16 + 2 * jp, c = 4 * k4 + 2 * s;
        W2p[idx] = make_float4(W2[j0 * 128 + c],     W2[(j0 + 1) * 128 + c],
                               W2[j0 * 128 + c + 1], W2[(j0 + 1) * 128 + c + 1]);
    }
}

__global__ __launch_bounds__(256) void deepfm_kernel(
    const int* __restrict__ user_id, const int* __restrict__ item_id,
    const int* __restrict__ gender_, const int* __restrict__ age_,
    const int* __restrict__ occ_, const int* __restrict__ genre_ids,
    const float* __restrict__ genre_mask, const float* __restrict__ dense,
    const float* __restrict__ fo_user, const float* __restrict__ fo_item,
    const float* __restrict__ fo_gender, const float* __restrict__ fo_age,
    const float* __restrict__ fo_occ, const float* __restrict__ fo_genre,
    const float* __restrict__ emb_user, const float* __restrict__ emb_item,
    const float* __restrict__ emb_gender, const float* __restrict__ emb_age,
    const float* __restrict__ emb_occ, const float* __restrict__ emb_genre,
    const float* __restrict__ dense_W, const float* __restrict__ dense_b,
    const float4* __restrict__ W1p, const float* __restrict__ b1,
    const float4* __restrict__ W2p, const float* __restrict__ b2,
    const float* __restrict__ Wout, const float* __restrict__ bout,
    float* __restrict__ out, int B)
{
    __shared__ float lds_di[ROWS_PER_BLOCK][DI_STRIDE];   // 13.1 KB; h1[16][132] overlays
    __shared__ float lds_rs[ROWS_PER_BLOCK];
    __shared__ float lds_part[ROWS_PER_BLOCK][4];

    const int tid = threadIdx.x;
    const int wid = tid >> 6;
    const int lane = tid & 63;
    const int blockRow0 = blockIdx.x * ROWS_PER_BLOCK;

    // ---------------- Phase A: gather + FM (wave owns 4 rows, SERIALIZED) ----------
    // unroll 1: one row's ~25 live VGPRs at a time; latency hidden by 16 waves/CU.
    {
        const int rowBase = blockRow0 + wid * ROWS_PER_WAVE;

        #pragma unroll 1
        for (int r = 0; r < ROWS_PER_WAVE; ++r) {
            int row = rowBase + r; if (row >= B) row = B - 1;
            const int ri = wid * ROWS_PER_WAVE + r;

            const int uid = user_id[row], iid = item_id[row];
            const int gg = gender_[row], aa = age_[row], oo = occ_[row];

            int gid[6]; float mk[6]; float msum = 0.f;
            #pragma unroll
            for (int t = 0; t < 6; ++t) {
                gid[t] = genre_ids[row * 6 + t];
                mk[t]  = genre_mask[row * 6 + t];
                msum  += mk[t];
            }
            const float inv_den = 1.0f / fmaxf(msum, 1.0f);

            float pe_sum = 0.f, pe_sq = 0.f;
            {
                float v = (lane < 32) ? emb_user[(size_t)uid * 32 + lane]
                                      : emb_item[(size_t)iid * 32 + (lane - 32)];
                lds_di[ri][lane] = v;
                pe_sum += v; pe_sq += v * v;
            }
            {
                float v = (lane < 32) ? emb_gender[gg * 32 + lane]
                                      : emb_age[aa * 32 + (lane - 32)];
                lds_di[ri][64 + lane] = v;
                pe_sum += v; pe_sq += v * v;
            }
            {
                float v;
                if (lane < 32) {
                    v = emb_occ[oo * 32 + lane];
                } else {
                    const int d = lane - 32;
                    float s = 0.f;
                    #pragma unroll
                    for (int t = 0; t < 6; ++t) s += mk[t] * emb_genre[gid[t] * 32 + d];
                    v = s * inv_den;
                }
                lds_di[ri][128 + lane] = v;
                pe_sum += v; pe_sq += v * v;
            }
            if (lane < 8) lds_di[ri][192 + lane] = dense[(size_t)row * 8 + lane];

            float s2 = pe_sum + __shfl_xor(pe_sum, 32);
            float ss = pe_sq  + __shfl_xor(pe_sq, 32);
            float t2 = 0.5f * (s2 * s2 - ss);
            #pragma unroll
            for (int off = 16; off >= 1; off >>= 1) t2 += __shfl_xor(t2, off);

            float fo = fo_user[uid] + fo_item[iid] + fo_gender[gg]
                     + fo_age[aa] + fo_occ[oo];
            float fg = 0.f;
            #pragma unroll
            for (int t = 0; t < 6; ++t) fg += mk[t] * fo_genre[gid[t]];
            fo += fg * inv_den;
            float dd = 0.f;
            #pragma unroll
            for (int j = 0; j < 8; ++j) dd += dense[(size_t)row * 8 + j] * dense_W[j];
            fo += dd + dense_b[0];

            if (lane == 0) lds_rs[ri] = fo + t2;
        }
    }
    __syncthreads();

    // ---------------- Phase B: h1 = relu(deep_in @ W1^T + b1) ----------------------
    // wave owns neurons [32*wid, 32*wid+32); jp1=lane&15 -> pair {2jp,2jp+1},
    // rh=lane>>4 -> rows {rh+4r}, r=0..3. Per k4: 4 act b128 (4 distinct rows,
    // conflict-free) + 2 weight b128 (coalesced) + 16 v_pk_fma.
    const int jp1 = lane & 15;
    const int rh  = lane >> 4;

    v2f acc[ROWS_PER_WAVE];
    #pragma unroll
    for (int r = 0; r < ROWS_PER_WAVE; ++r) acc[r] = bc2(0.f);

    {
        const float4* __restrict__ W1b = W1p + wid * 1600;
        const float4* __restrict__ dv = reinterpret_cast<const float4*>(&lds_di[0][0]); // stride 51

        #pragma unroll 2
        for (int k4 = 0; k4 < 50; ++k4) {
            const float4 wa = W1b[(k4 * 16 + jp1) * 2 + 0];   // {j0k0,j1k0,j0k1,j1k1}
            const float4 wb = W1b[(k4 * 16 + jp1) * 2 + 1];   // {j0k2,j1k2,j0k3,j1k3}
            const v2f w0 = { wa.x, wa.y }, w1 = { wa.z, wa.w };
            const v2f w2 = { wb.x, wb.y }, w3 = { wb.z, wb.w };
            #pragma unroll
            for (int r = 0; r < ROWS_PER_WAVE; ++r) {
                const float4 a = dv[(rh + 4 * r) * 51 + k4];
                acc[r] = __builtin_elementwise_fma(w0, bc2(a.x), acc[r]);
                acc[r] = __builtin_elementwise_fma(w1, bc2(a.y), acc[r]);
                acc[r] = __builtin_elementwise_fma(w2, bc2(a.z), acc[r]);
                acc[r] = __builtin_elementwise_fma(w3, bc2(a.w), acc[r]);
            }
        }
    }
    __syncthreads();   // all deep_in reads done; overlay h1

    float* __restrict__ h1b = &lds_di[0][0];   // h1[row][j] at row*132 + j
    {
        const int j0 = wid * 32 + 2 * jp1;
        const float2 bb = *reinterpret_cast<const float2*>(b1 + j0);
        #pragma unroll
        for (int r = 0; r < ROWS_PER_WAVE; ++r) {
            const int row = rh + 4 * r;
            reinterpret_cast<float2*>(h1b)[(row * H1_STRIDE + j0) >> 1] =
                make_float2(relu1(acc[r].x + bb.x), relu1(acc[r].y + bb.y));
        }
    }
    __syncthreads();

    // ---------------- Phase C: h2 = relu(h1 @ W2^T + b2) ---------------------------
    // wave owns neurons [16*wid,16*wid+16); jp2=lane&7 -> pair, rh2=lane>>3 ->
    // rows {rh2+8t}, t=0..1. Conflict-free via stride 132.
    const int jp2 = lane & 7;
    const int rh2 = lane >> 3;

    v2f acc2[2];
    acc2[0] = bc2(0.f); acc2[1] = bc2(0.f);

    {
        const float4* __restrict__ W2b = W2p + wid * 512;
        const float4* __restrict__ h1v = reinterpret_cast<const float4*>(h1b); // stride 33

        #pragma unroll 2
        for (int k4 = 0; k4 < 32; ++k4) {
            const float4 wa = W2b[(k4 * 8 + jp2) * 2 + 0];
            const float4 wb = W2b[(k4 * 8 + jp2) * 2 + 1];
            const v2f w0 = { wa.x, wa.y }, w1 = { wa.z, wa.w };
            const v2f w2 = { wb.x, wb.y }, w3 = { wb.z, wb.w };
            #pragma unroll
            for (int t = 0; t < 2; ++t) {
                const float4 h = h1v[(rh2 + 8 * t) * 33 + k4];
                acc2[t] = __builtin_elementwise_fma(w0, bc2(h.x), acc2[t]);
                acc2[t] = __builtin_elementwise_fma(w1, bc2(h.y), acc2[t]);
                acc2[t] = __builtin_elementwise_fma(w2, bc2(h.z), acc2[t]);
                acc2[t] = __builtin_elementwise_fma(w3, bc2(h.w), acc2[t]);
            }
        }
    }

    // ---------------- Phase D: Wout dot + combine ----------------------------------
    {
        const int j0 = wid * 16 + 2 * jp2;
        const float2 bb2 = *reinterpret_cast<const float2*>(b2 + j0);
        const float2 wo  = *reinterpret_cast<const float2*>(Wout + j0);
        #pragma unroll
        for (int t = 0; t < 2; ++t) {
            const float h2x = relu1(acc2[t].x + bb2.x);
            const float h2y = relu1(acc2[t].y + bb2.y);
            float v = wo.x * h2x + wo.y * h2y;
            v += __shfl_xor(v, 1); v += __shfl_xor(v, 2); v += __shfl_xor(v, 4);
            if (jp2 == 0) lds_part[rh2 + 8 * t][wid] = v;
        }
    }
    __syncthreads();

    if (tid < ROWS_PER_BLOCK) {
        const int row = blockRow0 + tid;
        if (row < B) {
            const float deep = lds_part[tid][0] + lds_part[tid][1]
                             + lds_part[tid][2] + lds_part[tid][3] + bout[0];
            out[row] = deep + lds_rs[tid];
        }
    }
}

extern "C" void kernel_launch(void* const* d_in, const int* in_sizes, int n_in,
                              void* d_out, int out_size, void* d_ws, size_t ws_size,
                              hipStream_t stream) {
    const int B = in_sizes[0];

    float4* W1p = reinterpret_cast<float4*>(d_ws);                  // 6400 float4 = 100 KB
    float4* W2p = reinterpret_cast<float4*>((char*)d_ws + 102400);  // 2048 float4 = 32 KB

    pack_weights<<<25, 256, 0, stream>>>(
        (const float*)d_in[22], (const float*)d_in[24], W1p, W2p);

    const int grid = (B + ROWS_PER_BLOCK - 1) / ROWS_PER_BLOCK;  // 1024 at B=16384
    deepfm_kernel<<<grid, 256, 0, stream>>>(
        (const int*)d_in[0],  (const int*)d_in[1],  (const int*)d_in[2],
        (const int*)d_in[3],  (const int*)d_in[4],  (const int*)d_in[5],
        (const float*)d_in[6],  (const float*)d_in[7],
        (const float*)d_in[8],  (const float*)d_in[9],  (const float*)d_in[10],
        (const float*)d_in[11], (const float*)d_in[12], (const float*)d_in[13],
        (const float*)d_in[14], (const float*)d_in[15], (const float*)d_in[16],
        (const float*)d_in[17], (const float*)d_in[18], (const float*)d_in[19],
        (const float*)d_in[20], (const float*)d_in[21],
        W1p, (const float*)d_in[23],
        W2p, (const float*)d_in[25],
        (const float*)d_in[26], (const float*)d_in[27],
        (float*)d_out, B);
}

// Round 9
// 248.191 us; speedup vs baseline: 1.2341x; 1.0282x over previous
//
#include <hip/hip_runtime.h>

// DeepFM fused ranker, fp32.
// R12 (resubmit — previous round failed on container acquisition, not kernel).
// Lane-parallel phase A. R11 fixed the VGPR balloon (unroll 1) but serialized
// 4 dependent gather chains per wave (id->emb, ~2x500cy each). Restructure:
// wave = 4 rows x 16 dim-pairs (rl=lane&3, dx=lane>>2). All rows' ids and all
// 11 float2 embedding gathers issue concurrently -> one latency window, ~1/3
// the instructions. FM second order reduces via shfl_xor 4/8/16/32 within the
// 16-lane row group; first-order scalars + dense dot distribute across spare
// dx lanes and ride the same tree. Phases B/C/D + geometry (ROWS16/grid1024/
// 256t, unroll-2 k4) = R11 verbatim (proven best, 255.2us).

typedef float v2f __attribute__((ext_vector_type(2)));
static __device__ __forceinline__ v2f bc2(float x) { v2f r; r.x = x; r.y = x; return r; }
static __device__ __forceinline__ float relu1(float x) { return fmaxf(x, 0.f); }

#define ROWS_PER_BLOCK 16
#define ROWS_PER_WAVE 4
#define DI_STRIDE 204            // floats; 51 float4
#define H1_STRIDE 132            // floats; 33 float4

// ---- pre-pass: pair-transposed packed weights (R4 layout) ----
__global__ void pack_weights(const float* __restrict__ W1, const float* __restrict__ W2,
                             float4* __restrict__ W1p, float4* __restrict__ W2p) {
    const int idx = blockIdx.x * blockDim.x + threadIdx.x;
    if (idx < 6400) {
        const int s = idx & 1, jp = (idx >> 1) & 15, k4 = (idx >> 5) % 50, w = idx / 1600;
        const int j0 = w * 32 + 2 * jp, c = 4 * k4 + 2 * s;
        W1p[idx] = make_float4(W1[j0 * 200 + c],     W1[(j0 + 1) * 200 + c],
                               W1[j0 * 200 + c + 1], W1[(j0 + 1) * 200 + c + 1]);
    }
    if (idx < 2048) {
        const int s = idx & 1, jp = (idx >> 1) & 7, k4 = (idx >> 4) & 31, w = idx >> 9;
        const int j0 = w * 16 + 2 * jp, c = 4 * k4 + 2 * s;
        W2p[idx] = make_float4(W2[j0 * 128 + c],     W2[(j0 + 1) * 128 + c],
                               W2[j0 * 128 + c + 1], W2[(j0 + 1) * 128 + c + 1]);
    }
}

__global__ __launch_bounds__(256) void deepfm_kernel(
    const int* __restrict__ user_id, const int* __restrict__ item_id,
    const int* __restrict__ gender_, const int* __restrict__ age_,
    const int* __restrict__ occ_, const int* __restrict__ genre_ids,
    const float* __restrict__ genre_mask, const float* __restrict__ dense,
    const float* __restrict__ fo_user, const float* __restrict__ fo_item,
    const float* __restrict__ fo_gender, const float* __restrict__ fo_age,
    const float* __restrict__ fo_occ, const float* __restrict__ fo_genre,
    const float* __restrict__ emb_user, const float* __restrict__ emb_item,
    const float* __restrict__ emb_gender, const float* __restrict__ emb_age,
    const float* __restrict__ emb_occ, const float* __restrict__ emb_genre,
    const float* __restrict__ dense_W, const float* __restrict__ dense_b,
    const float4* __restrict__ W1p, const float* __restrict__ b1,
    const float4* __restrict__ W2p, const float* __restrict__ b2,
    const float* __restrict__ Wout, const float* __restrict__ bout,
    float* __restrict__ out, int B)
{
    __shared__ float lds_di[ROWS_PER_BLOCK][DI_STRIDE];   // 13.1 KB; h1[16][132] overlays
    __shared__ float lds_rs[ROWS_PER_BLOCK];
    __shared__ float lds_part[ROWS_PER_BLOCK][4];

    const int tid = threadIdx.x;
    const int wid = tid >> 6;
    const int lane = tid & 63;
    const int blockRow0 = blockIdx.x * ROWS_PER_BLOCK;

    // ---------------- Phase A: 4 rows x 16 dim-pairs, fully concurrent ------------
    {
        const int rl = lane & 3;          // row within wave
        const int dx = lane >> 2;         // dim-pair index 0..15
        const int d0 = 2 * dx;            // dims {d0, d0+1}

        int row = blockRow0 + wid * ROWS_PER_WAVE + rl;
        if (row >= B) row = B - 1;
        const int ri = wid * ROWS_PER_WAVE + rl;

        const int uid = user_id[row], iid = item_id[row];
        const int gg = gender_[row], aa = age_[row], oo = occ_[row];

        int gid[6]; float mk[6]; float msum = 0.f;
        #pragma unroll
        for (int t = 0; t < 6; ++t) {
            gid[t] = genre_ids[row * 6 + t];
            mk[t]  = genre_mask[row * 6 + t];
            msum  += mk[t];
        }
        const float inv_den = 1.0f / fmaxf(msum, 1.0f);

        // 11 independent float2 gathers — one latency window for all 4 rows
        const float2 eu = *reinterpret_cast<const float2*>(emb_user + (size_t)uid * 32 + d0);
        const float2 ei = *reinterpret_cast<const float2*>(emb_item + (size_t)iid * 32 + d0);
        const float2 eg = *reinterpret_cast<const float2*>(emb_gender + gg * 32 + d0);
        const float2 ea = *reinterpret_cast<const float2*>(emb_age + aa * 32 + d0);
        const float2 eo = *reinterpret_cast<const float2*>(emb_occ + oo * 32 + d0);
        float epx = 0.f, epy = 0.f;
        #pragma unroll
        for (int t = 0; t < 6; ++t) {
            const float2 g = *reinterpret_cast<const float2*>(emb_genre + gid[t] * 32 + d0);
            epx += mk[t] * g.x; epy += mk[t] * g.y;
        }
        epx *= inv_den; epy *= inv_den;

        // deep_in layout: user 0-31 | item 32-63 | gender 64-95 | age 96-127 |
        //                 occ 128-159 | genre 160-191 | dense 192-199
        *reinterpret_cast<float2*>(&lds_di[ri][d0])       = eu;
        *reinterpret_cast<float2*>(&lds_di[ri][32 + d0])  = ei;
        *reinterpret_cast<float2*>(&lds_di[ri][64 + d0])  = eg;
        *reinterpret_cast<float2*>(&lds_di[ri][96 + d0])  = ea;
        *reinterpret_cast<float2*>(&lds_di[ri][128 + d0]) = eo;
        *reinterpret_cast<float2*>(&lds_di[ri][160 + d0]) = make_float2(epx, epy);

        // FM second order: per-lane over its 2 dims
        const float sx = eu.x + ei.x + eg.x + ea.x + eo.x + epx;
        const float sy = eu.y + ei.y + eg.y + ea.y + eo.y + epy;
        const float qx = eu.x*eu.x + ei.x*ei.x + eg.x*eg.x + ea.x*ea.x + eo.x*eo.x + epx*epx;
        const float qy = eu.y*eu.y + ei.y*ei.y + eg.y*eg.y + ea.y*ea.y + eo.y*eo.y + epy*epy;
        float c = 0.5f * ((sx * sx - qx) + (sy * sy - qy));

        // distributed first-order + dense
        if (dx < 4) {
            const float2 dv = *reinterpret_cast<const float2*>(dense + (size_t)row * 8 + d0);
            *reinterpret_cast<float2*>(&lds_di[ri][192 + d0]) = dv;
            c += dv.x * dense_W[d0] + dv.y * dense_W[d0 + 1];
        } else if (dx == 8)  c += fo_user[uid];
        else if (dx == 9)  c += fo_item[iid];
        else if (dx == 10) c += fo_gender[gg];
        else if (dx == 11) c += fo_age[aa];
        else if (dx == 12) c += fo_occ[oo];
        else if (dx == 13) {
            float fg = 0.f;
            #pragma unroll
            for (int t = 0; t < 6; ++t) fg += mk[t] * fo_genre[gid[t]];
            c += fg * inv_den;
        } else if (dx == 14) c += dense_b[0];

        // reduce across the 16-lane row group (stride 4)
        c += __shfl_xor(c, 4); c += __shfl_xor(c, 8);
        c += __shfl_xor(c, 16); c += __shfl_xor(c, 32);
        if (dx == 0) lds_rs[ri] = c;
    }
    __syncthreads();

    // ---------------- Phase B: h1 = relu(deep_in @ W1^T + b1) ----------------------
    // wave owns neurons [32*wid, 32*wid+32); jp1=lane&15 -> pair {2jp,2jp+1},
    // rh=lane>>4 -> rows {rh+4r}, r=0..3.
    const int jp1 = lane & 15;
    const int rh  = lane >> 4;

    v2f acc[ROWS_PER_WAVE];
    #pragma unroll
    for (int r = 0; r < ROWS_PER_WAVE; ++r) acc[r] = bc2(0.f);

    {
        const float4* __restrict__ W1b = W1p + wid * 1600;
        const float4* __restrict__ dv = reinterpret_cast<const float4*>(&lds_di[0][0]); // stride 51

        #pragma unroll 2
        for (int k4 = 0; k4 < 50; ++k4) {
            const float4 wa = W1b[(k4 * 16 + jp1) * 2 + 0];   // {j0k0,j1k0,j0k1,j1k1}
            const float4 wb = W1b[(k4 * 16 + jp1) * 2 + 1];   // {j0k2,j1k2,j0k3,j1k3}
            const v2f w0 = { wa.x, wa.y }, w1 = { wa.z, wa.w };
            const v2f w2 = { wb.x, wb.y }, w3 = { wb.z, wb.w };
            #pragma unroll
            for (int r = 0; r < ROWS_PER_WAVE; ++r) {
                const float4 a = dv[(rh + 4 * r) * 51 + k4];
                acc[r] = __builtin_elementwise_fma(w0, bc2(a.x), acc[r]);
                acc[r] = __builtin_elementwise_fma(w1, bc2(a.y), acc[r]);
                acc[r] = __builtin_elementwise_fma(w2, bc2(a.z), acc[r]);
                acc[r] = __builtin_elementwise_fma(w3, bc2(a.w), acc[r]);
            }
        }
    }
    __syncthreads();   // all deep_in reads done; overlay h1

    float* __restrict__ h1b = &lds_di[0][0];   // h1[row][j] at row*132 + j
    {
        const int j0 = wid * 32 + 2 * jp1;
        const float2 bb = *reinterpret_cast<const float2*>(b1 + j0);
        #pragma unroll
        for (int r = 0; r < ROWS_PER_WAVE; ++r) {
            const int row = rh + 4 * r;
            reinterpret_cast<float2*>(h1b)[(row * H1_STRIDE + j0) >> 1] =
                make_float2(relu1(acc[r].x + bb.x), relu1(acc[r].y + bb.y));
        }
    }
    __syncthreads();

    // ---------------- Phase C: h2 = relu(h1 @ W2^T + b2) ---------------------------
    const int jp2 = lane & 7;
    const int rh2 = lane >> 3;

    v2f acc2[2];
    acc2[0] = bc2(0.f); acc2[1] = bc2(0.f);

    {
        const float4* __restrict__ W2b = W2p + wid * 512;
        const float4* __restrict__ h1v = reinterpret_cast<const float4*>(h1b); // stride 33

        #pragma unroll 2
        for (int k4 = 0; k4 < 32; ++k4) {
            const float4 wa = W2b[(k4 * 8 + jp2) * 2 + 0];
            const float4 wb = W2b[(k4 * 8 + jp2) * 2 + 1];
            const v2f w0 = { wa.x, wa.y }, w1 = { wa.z, wa.w };
            const v2f w2 = { wb.x, wb.y }, w3 = { wb.z, wb.w };
            #pragma unroll
            for (int t = 0; t < 2; ++t) {
                const float4 h = h1v[(rh2 + 8 * t) * 33 + k4];
                acc2[t] = __builtin_elementwise_fma(w0, bc2(h.x), acc2[t]);
                acc2[t] = __builtin_elementwise_fma(w1, bc2(h.y), acc2[t]);
                acc2[t] = __builtin_elementwise_fma(w2, bc2(h.z), acc2[t]);
                acc2[t] = __builtin_elementwise_fma(w3, bc2(h.w), acc2[t]);
            }
        }
    }

    // ---------------- Phase D: Wout dot + combine ----------------------------------
    {
        const int j0 = wid * 16 + 2 * jp2;
        const float2 bb2 = *reinterpret_cast<const float2*>(b2 + j0);
        const float2 wo  = *reinterpret_cast<const float2*>(Wout + j0);
        #pragma unroll
        for (int t = 0; t < 2; ++t) {
            const float h2x = relu1(acc2[t].x + bb2.x);
            const float h2y = relu1(acc2[t].y + bb2.y);
            float v = wo.x * h2x + wo.y * h2y;
            v += __shfl_xor(v, 1); v += __shfl_xor(v, 2); v += __shfl_xor(v, 4);
            if (jp2 == 0) lds_part[rh2 + 8 * t][wid] = v;
        }
    }
    __syncthreads();

    if (tid < ROWS_PER_BLOCK) {
        const int row = blockRow0 + tid;
        if (row < B) {
            const float deep = lds_part[tid][0] + lds_part[tid][1]
                             + lds_part[tid][2] + lds_part[tid][3] + bout[0];
            out[row] = deep + lds_rs[tid];
        }
    }
}

extern "C" void kernel_launch(void* const* d_in, const int* in_sizes, int n_in,
                              void* d_out, int out_size, void* d_ws, size_t ws_size,
                              hipStream_t stream) {
    const int B = in_sizes[0];

    float4* W1p = reinterpret_cast<float4*>(d_ws);                  // 6400 float4 = 100 KB
    float4* W2p = reinterpret_cast<float4*>((char*)d_ws + 102400);  // 2048 float4 = 32 KB

    pack_weights<<<25, 256, 0, stream>>>(
        (const float*)d_in[22], (const float*)d_in[24], W1p, W2p);

    const int grid = (B + ROWS_PER_BLOCK - 1) / ROWS_PER_BLOCK;  // 1024 at B=16384
    deepfm_kernel<<<grid, 256, 0, stream>>>(
        (const int*)d_in[0],  (const int*)d_in[1],  (const int*)d_in[2],
        (const int*)d_in[3],  (const int*)d_in[4],  (const int*)d_in[5],
        (const float*)d_in[6],  (const float*)d_in[7],
        (const float*)d_in[8],  (const float*)d_in[9],  (const float*)d_in[10],
        (const float*)d_in[11], (const float*)d_in[12], (const float*)d_in[13],
        (const float*)d_in[14], (const float*)d_in[15], (const float*)d_in[16],
        (const float*)d_in[17], (const float*)d_in[18], (const float*)d_in[19],
        (const float*)d_in[20], (const float*)d_in[21],
        W1p, (const float*)d_in[23],
        W2p, (const float*)d_in[25],
        (const float*)d_in[26], (const float*)d_in[27],
        (float*)d_out, B);
}